// Round 13
// baseline (142.598 us; speedup 1.0000x reference)
//
#include <hip/hip_runtime.h>
#include <math.h>

#define NPTS_PER_WAVE 6

typedef _Float16 h8 __attribute__((ext_vector_type(8)));
typedef _Float16 h2 __attribute__((ext_vector_type(2)));
typedef __fp16   fp16x2 __attribute__((ext_vector_type(2)));
typedef float    f4 __attribute__((ext_vector_type(4)));
typedef float    f32x16 __attribute__((ext_vector_type(16)));
typedef unsigned int uint32;

// cfg constants
#define CSE_C 0.5f
#define CLE_C 0.00574f
#define DCOEF (CSE_C - CLE_C)          // 0.49426
#define KCOEF (1.0f - CSE_C + CLE_C)   // 0.50574

__device__ __forceinline__ float tanh_fast(float xx) {
    float e = __expf(2.0f * xx);
    float r = __builtin_amdgcn_rcpf(e + 1.0f);
    return fmaf(-2.0f, r, 1.0f);
}
__device__ __forceinline__ unsigned short f2h(float a) {
    union { _Float16 h; unsigned short u; } ua; ua.h = (_Float16)a; return ua.u;
}
__device__ __forceinline__ h2 pkrtz(float a, float b) {
    union { fp16x2 f; h2 h; } x; x.f = __builtin_amdgcn_cvt_pkrtz(a, b); return x.h;
}
__device__ __forceinline__ uint32 pk2h(float a, float b) {
    union { h2 h; uint32 u; } x; x.h = pkrtz(a, b); return x.u;
}
__device__ __forceinline__ h8 h8_from4(uint32 a, uint32 b, uint32 c, uint32 d) {
    union { uint32 u[4]; h8 v; } x; x.u[0] = a; x.u[1] = b; x.u[2] = c; x.u[3] = d;
    return x.v;
}

// ---------------------------------------------------------------------------
// Prep: Wh (4,128,128 f32) -> A-fragment-ordered f16 W^T for 32x32x16 MFMA.
// A-frag: lane holds row m = lane&31, k = (lane>>5)*8 + e (8 contig f16).
//   Wp[ ((L*4+jt)*8+ks)*256 + lane*4 + d ] packs
//   (k0 = ks*16+(lane>>5)*8+2d, k0+1) at m = jt*32+(lane&31):
//   value = W^T[m,k] = Wh[L][k][jout=m]
// ---------------------------------------------------------------------------
extern "C" __global__ __launch_bounds__(256)
void pinn_prep(const float* __restrict__ Wh, uint32* __restrict__ Wp)
{
    int gid  = blockIdx.x * 256 + threadIdx.x;       // 0..32767
    int d    = gid & 3;
    int lane = (gid >> 2) & 63;
    int ks   = (gid >> 8) & 7;
    int jt   = (gid >> 11) & 3;
    int L    = gid >> 13;
    int k0   = ks * 16 + (lane >> 5) * 8 + 2 * d;
    int m    = jt * 32 + (lane & 31);
    float w0 = Wh[(L * 128 + k0) * 128 + m];
    float w1 = Wh[(L * 128 + k0 + 1) * 128 + m];
    Wp[gid] = pk2h(w0, w1);
}

// ---------------------------------------------------------------------------
// Main: barrier-free, 1 wave/block, 6 points = 12 branch-points (bp),
// 5 channels each (value, d/dt, d/dx0, d/dx1, laplacian).
// 32x32x16 MFMA: 2 col-tiles of 32 (6 bp x 5 ch + 2 pad per tile).
// H row = ct*32 + (b%6)*5 + ch; H in LDS [64][136] f16 (17408 B).
// bf (2x8 b128) register-held per layer (read before phase-A overwrite).
// W A-frags streamed from L2, 4-deep rolling prefetch (fi&3; 32%4=0 so
// cross-layer prefetch lands in the right slots).
// ---------------------------------------------------------------------------
extern "C" __global__ __launch_bounds__(64, 2)
void pinn_mfma(const float* __restrict__ x, const float* __restrict__ t,
               const float* __restrict__ B, const uint32* __restrict__ Wp,
               const float* __restrict__ bh, const float* __restrict__ Wout,
               const float* __restrict__ bout, float* __restrict__ out, int npts)
{
    __shared__ __align__(16) unsigned short H[64][136];   // 17408 B

    const int lane = threadIdx.x;        // 0..63 (one wave)
    const int m31  = lane & 31;
    const int kg8  = (lane >> 5) * 8;    // k sub-offset (shorts)
    const int base_pt = blockIdx.x * NPTS_PER_WAVE;

    unsigned short* Hb = &H[0][0];

    // W frags: 4-deep rolling buffer; first 4 issued before the embed so
    // their L2 latency hides under the embedding math.
    uint4 wf[4];
    {
        const uint4* W0 = (const uint4*)Wp;
        #pragma unroll
        for (int p = 0; p < 4; ++p) wf[p] = W0[p * 64 + lane];
    }

    // ---------------- embedding (writes layer-0 H) ----------------
    {
        const float TWO_PI = 6.28318530717958647692f;
        const float Br0 = B[lane], Br1 = B[64 + lane], Br2 = B[128 + lane];
        const float b0 = TWO_PI * Br0, b1 = TWO_PI * Br1, b2 = TWO_PI * Br2;
        const float bsq = fmaf(b0, b0, b1 * b1);
        // zero the 4 pad rows (cols 30,31 of each tile never used downstream)
        Hb[30 * 136 + lane] = 0; Hb[30 * 136 + 64 + lane] = 0;
        Hb[31 * 136 + lane] = 0; Hb[31 * 136 + 64 + lane] = 0;
        Hb[62 * 136 + lane] = 0; Hb[62 * 136 + 64 + lane] = 0;
        Hb[63 * 136 + lane] = 0; Hb[63 * 136 + 64 + lane] = 0;
        #pragma unroll
        for (int pl = 0; pl < 6; ++pl) {
            int pt = base_pt + pl; if (pt > npts - 1) pt = npts - 1;
            const float2 xx = *(const float2*)&x[2 * pt];
            const float tt = t[pt];
            const float uc = fmaf(xx.y, Br1, tt * Br2);   // revolutions
            const float ux = xx.x * Br0;
            #pragma unroll
            for (int mir = 0; mir < 2; ++mir) {
                float u = mir ? (uc - ux) : (uc + ux);
                float r = u - floorf(u);
                float sf = __builtin_amdgcn_sinf(r);      // sin(2*pi*u)
                float cf = __builtin_amdgcn_cosf(r);      // cos(2*pi*u)
                const int b  = pl * 2 + mir;              // bp 0..11
                const int rs = (b / 6) * 32 + (b % 6) * 5;
                Hb[(rs + 0) * 136 + lane] = f2h(sf);
                Hb[(rs + 1) * 136 + lane] = f2h(cf * b2);
                Hb[(rs + 2) * 136 + lane] = f2h(cf * b0);
                Hb[(rs + 3) * 136 + lane] = f2h(cf * b1);
                Hb[(rs + 4) * 136 + lane] = f2h(-sf * bsq);
                Hb[(rs + 0) * 136 + 64 + lane] = f2h(cf);
                Hb[(rs + 1) * 136 + 64 + lane] = f2h(-sf * b2);
                Hb[(rs + 2) * 136 + 64 + lane] = f2h(-sf * b0);
                Hb[(rs + 3) * 136 + 64 + lane] = f2h(-sf * b1);
                Hb[(rs + 4) * 136 + 64 + lane] = f2h(-cf * bsq);
            }
        }
    }
    asm volatile("s_waitcnt lgkmcnt(0)" ::: "memory");

    // ---------------- hidden layers ----------------
    for (int L = 0; L < 4; ++L) {
        // B-fragments for both col-tiles, all 8 k-steps, held in registers
        // (must be read before any phase-A write overwrites H columns).
        h8 bf0[8], bf1[8];
        #pragma unroll
        for (int ks = 0; ks < 8; ++ks) {
            bf0[ks] = *(const h8*)&Hb[m31 * 136 + ks * 16 + kg8];
            bf1[ks] = *(const h8*)&Hb[(32 + m31) * 136 + ks * 16 + kg8];
        }

        const uint4* WL = (const uint4*)Wp + (size_t)L * 2048;   // layer base
        const uint4* WN = WL + 2048;                              // next layer

        #pragma unroll
        for (int jt = 0; jt < 4; ++jt) {
            f32x16 a0 = {0.f,0.f,0.f,0.f,0.f,0.f,0.f,0.f,0.f,0.f,0.f,0.f,0.f,0.f,0.f,0.f};
            f32x16 a1 = {0.f,0.f,0.f,0.f,0.f,0.f,0.f,0.f,0.f,0.f,0.f,0.f,0.f,0.f,0.f,0.f};
            #pragma unroll
            for (int ks = 0; ks < 8; ++ks) {
                const int fi = jt * 8 + ks;
                union { uint4 u; h8 v; } af;
                af.u = wf[fi & 3];
                if (fi < 28)      wf[fi & 3] = WL[(fi + 4) * 64 + lane];
                else if (L < 3)   wf[fi & 3] = WN[(fi - 28) * 64 + lane];
                a0 = __builtin_amdgcn_mfma_f32_32x32x16_f16(af.v, bf0[ks], a0, 0, 0, 0);
                a1 = __builtin_amdgcn_mfma_f32_32x32x16_f16(af.v, bf1[ks], a1, 0, 0, 0);
            }
            // phase A: raw pre-activations. C layout: col n = lane&31 (=H row
            // within tile), row m = (reg&3)+8*(reg>>2)+4*(lane>>5) (=j).
            #pragma unroll
            for (int q = 0; q < 4; ++q) {
                union { h2 h[2]; uint2 u; } w0, w1;
                w0.h[0] = pkrtz(a0[4*q+0], a0[4*q+1]);
                w0.h[1] = pkrtz(a0[4*q+2], a0[4*q+3]);
                w1.h[0] = pkrtz(a1[4*q+0], a1[4*q+1]);
                w1.h[1] = pkrtz(a1[4*q+2], a1[4*q+3]);
                const int jof = jt * 32 + q * 8 + (lane >> 5) * 4;
                *(uint2*)&Hb[m31 * 136 + jof]        = w0.u;
                *(uint2*)&Hb[(32 + m31) * 136 + jof] = w1.u;
            }
        }
        asm volatile("s_waitcnt lgkmcnt(0)" ::: "memory");

        // phase B: lane-private j-columns (j = 2*lane, 2*lane+1), packed f16.
        // Bias (value channel only) applied here.
        {
            const int jb = 2 * lane;
            const float2 bj = *(const float2*)&bh[L * 128 + jb];
            const h2 bias2 = pkrtz(bj.x, bj.y);
            const h2 m2 = {(_Float16)(-2.0f), (_Float16)(-2.0f)};
            #pragma unroll
            for (int b = 0; b < 12; ++b) {
                const int rs = (b / 6) * 32 + (b % 6) * 5;
                h2 vp = *(const h2*)&Hb[(rs + 0) * 136 + jb];
                h2 tp = *(const h2*)&Hb[(rs + 1) * 136 + jb];
                h2 pp = *(const h2*)&Hb[(rs + 2) * 136 + jb];
                h2 qp = *(const h2*)&Hb[(rs + 3) * 136 + jb];
                h2 Lp = *(const h2*)&Hb[(rs + 4) * 136 + jb];
                vp = vp + bias2;
                float y0 = tanh_fast((float)vp[0]);
                float y1 = tanh_fast((float)vp[1]);
                h2 yp = pkrtz(y0, y1);
                h2 sp = pkrtz(fmaf(-y0, y0, 1.f), fmaf(-y1, y1, 1.f));
                h2 qq = __builtin_elementwise_fma(pp, pp, qp * qp);
                h2 Ln = sp * __builtin_elementwise_fma(yp * m2, qq, Lp);
                *(h2*)&Hb[(rs + 0) * 136 + jb] = yp;
                *(h2*)&Hb[(rs + 1) * 136 + jb] = sp * tp;
                *(h2*)&Hb[(rs + 2) * 136 + jb] = sp * pp;
                *(h2*)&Hb[(rs + 3) * 136 + jb] = sp * qp;
                *(h2*)&Hb[(rs + 4) * 136 + jb] = Ln;
            }
        }
        asm volatile("s_waitcnt lgkmcnt(0)" ::: "memory");
    }

    // ---------------- output layer via MFMA + residual ----------------
    {
        // A = Wout^T (2x128, rows 2..31 zeroed), built in-register
        h8 afo[8];
        const float sel = (m31 < 2) ? 1.0f : 0.0f;
        const int   mi  = m31 & 1;
        #pragma unroll
        for (int ks = 0; ks < 8; ++ks) {
            uint32 u[4];
            #pragma unroll
            for (int d = 0; d < 4; ++d) {
                const int k0 = ks * 16 + kg8 + 2 * d;
                u[d] = pk2h(Wout[k0 * 2 + mi] * sel, Wout[(k0 + 1) * 2 + mi] * sel);
            }
            afo[ks] = h8_from4(u[0], u[1], u[2], u[3]);
        }
        f32x16 a0 = {0.f,0.f,0.f,0.f,0.f,0.f,0.f,0.f,0.f,0.f,0.f,0.f,0.f,0.f,0.f,0.f};
        f32x16 a1 = {0.f,0.f,0.f,0.f,0.f,0.f,0.f,0.f,0.f,0.f,0.f,0.f,0.f,0.f,0.f,0.f};
        #pragma unroll
        for (int ks = 0; ks < 8; ++ks) {
            h8 b0 = *(const h8*)&Hb[m31 * 136 + ks * 16 + kg8];
            h8 b1 = *(const h8*)&Hb[(32 + m31) * 136 + ks * 16 + kg8];
            a0 = __builtin_amdgcn_mfma_f32_32x32x16_f16(afo[ks], b0, a0, 0, 0, 0);
            a1 = __builtin_amdgcn_mfma_f32_32x32x16_f16(afo[ks], b1, a1, 0, 0, 0);
        }
        // Lanes 0..31 hold C rows 0 (=o0, reg0) and 1 (=o1, reg1) for col n=lane.
        // S[n*4 + 2*ct + {0=o0,1=o1}]
        float* S = (float*)Hb;        // 512 B scratch, H no longer needed
        if (lane < 32) {
            f4 pack = {a0[0], a0[1], a1[0], a1[1]};
            *(f4*)&S[lane * 4] = pack;
        }
        asm volatile("s_waitcnt lgkmcnt(0)" ::: "memory");

        if (lane < 6) {
            int pt = base_pt + lane;
            if (pt < npts) {
                float bo0 = bout[0], bo1 = bout[1];
                float ph = 0.f, cv = 0.f, ptd = 0.f, lp = 0.f;
                #pragma unroll
                for (int br = 0; br < 2; ++br) {
                    int b  = 2 * lane + br;
                    int ct = b / 6;
                    int n5 = (b % 6) * 5;
                    float o0v = S[(n5 + 0) * 4 + 2 * ct] + bo0;
                    float o0t = S[(n5 + 1) * 4 + 2 * ct];
                    float o0p = S[(n5 + 2) * 4 + 2 * ct];
                    float o0q = S[(n5 + 3) * 4 + 2 * ct];
                    float o0L = S[(n5 + 4) * 4 + 2 * ct];
                    float o1v = S[(n5 + 0) * 4 + 2 * ct + 1] + bo1;
                    float T = tanh_fast(o0v);
                    float p = fmaf(0.5f, T, 0.5f);
                    float s = 0.5f * fmaf(-T, T, 1.f);
                    float lap = s * o0L - 2.f * T * s * fmaf(o0p, o0p, o0q * o0q);
                    float cl = KCOEF * fmaf(0.5f, tanh_fast(o1v), 0.5f);
                    float cb = fmaf(DCOEF, (-2.f * p + 3.f) * p * p, cl);
                    ph  += 0.5f * p;
                    cv  += 0.5f * cb;
                    ptd += 0.5f * s * o0t;
                    lp  += 0.5f * lap;
                }
                float hph = (-2.f * ph + 3.f) * ph * ph;
                float dh  = 6.f * ph * (1.f - ph);
                float dg  = ((4.f * ph - 6.f) * ph + 2.f) * ph;
                float ac  = ptd
                          - 2.f * ((cv - hph * DCOEF - CLE_C) * DCOEF) * dh
                          + dg
                          - 0.01f * lp;
                out[pt] = ac;
            }
        }
    }
}

extern "C" void kernel_launch(void* const* d_in, const int* in_sizes, int n_in,
                              void* d_out, int out_size, void* d_ws, size_t ws_size,
                              hipStream_t stream) {
    const float* x    = (const float*)d_in[0];
    const float* t    = (const float*)d_in[1];
    const float* B    = (const float*)d_in[2];
    const float* Wh   = (const float*)d_in[3];
    const float* bh   = (const float*)d_in[4];
    const float* Wout = (const float*)d_in[5];
    const float* bout = (const float*)d_in[6];
    float* out = (float*)d_out;
    uint32* Wp = (uint32*)d_ws;                       // 128 KB scratch

    const int npts = in_sizes[0] / 2;
    hipLaunchKernelGGL(pinn_prep, dim3(128), dim3(256), 0, stream, Wh, Wp);
    const int nb = (npts + NPTS_PER_WAVE - 1) / NPTS_PER_WAVE;
    hipLaunchKernelGGL(pinn_mfma, dim3(nb), dim3(64), 0, stream,
                       x, t, B, Wp, bh, Wout, bout, out, npts);
}

// Round 14
// 139.609 us; speedup vs baseline: 1.0214x; 1.0214x over previous
//
#include <hip/hip_runtime.h>
#include <math.h>

#define NPTS_PER_WAVE 6

typedef _Float16 h8 __attribute__((ext_vector_type(8)));
typedef _Float16 h2 __attribute__((ext_vector_type(2)));
typedef __fp16   fp16x2 __attribute__((ext_vector_type(2)));
typedef float    f4 __attribute__((ext_vector_type(4)));
typedef float    f32x16 __attribute__((ext_vector_type(16)));
typedef unsigned int uint32;

// cfg constants
#define CSE_C 0.5f
#define CLE_C 0.00574f
#define DCOEF (CSE_C - CLE_C)          // 0.49426
#define KCOEF (1.0f - CSE_C + CLE_C)   // 0.50574

__device__ __forceinline__ float tanh_fast(float xx) {
    float e = __expf(2.0f * xx);
    float r = __builtin_amdgcn_rcpf(e + 1.0f);
    return fmaf(-2.0f, r, 1.0f);
}
__device__ __forceinline__ unsigned short f2h(float a) {
    union { _Float16 h; unsigned short u; } ua; ua.h = (_Float16)a; return ua.u;
}
__device__ __forceinline__ h2 pkrtz(float a, float b) {
    union { fp16x2 f; h2 h; } x; x.f = __builtin_amdgcn_cvt_pkrtz(a, b); return x.h;
}
__device__ __forceinline__ uint32 pk2h(float a, float b) {
    union { h2 h; uint32 u; } x; x.h = pkrtz(a, b); return x.u;
}
__device__ __forceinline__ h8 h8_from4(uint32 a, uint32 b, uint32 c, uint32 d) {
    union { uint32 u[4]; h8 v; } x; x.u[0] = a; x.u[1] = b; x.u[2] = c; x.u[3] = d;
    return x.v;
}

// ---------------------------------------------------------------------------
// Prep: Wh (4,128,128 f32) -> A-fragment-ordered f16 W^T for 32x32x16 MFMA.
// A-frag: lane holds row m = lane&31, k = (lane>>5)*8 + e (8 contig f16).
//   Wp[ ((L*4+jt)*8+ks)*256 + lane*4 + d ] packs
//   (k0 = ks*16+(lane>>5)*8+2d, k0+1) at m = jt*32+(lane&31):
//   value = W^T[m,k] = Wh[L][k][jout=m]
// ---------------------------------------------------------------------------
extern "C" __global__ __launch_bounds__(256)
void pinn_prep(const float* __restrict__ Wh, uint32* __restrict__ Wp)
{
    int gid  = blockIdx.x * 256 + threadIdx.x;       // 0..32767
    int d    = gid & 3;
    int lane = (gid >> 2) & 63;
    int ks   = (gid >> 8) & 7;
    int jt   = (gid >> 11) & 3;
    int L    = gid >> 13;
    int k0   = ks * 16 + (lane >> 5) * 8 + 2 * d;
    int m    = jt * 32 + (lane & 31);
    float w0 = Wh[(L * 128 + k0) * 128 + m];
    float w1 = Wh[(L * 128 + k0 + 1) * 128 + m];
    Wp[gid] = pk2h(w0, w1);
}

// ---------------------------------------------------------------------------
// Main: barrier-free, 1 wave/block, 6 points = 12 branch-points (bp),
// 5 channels each (value, d/dt, d/dx0, d/dx1, laplacian).
// 32x32x16 MFMA, 2 col-tiles of 32. Accumulators SPLIT over even/odd ks
// (a0a/a0b, a1a/a1b) -> 4 independent chains of 4, same-chain issue
// spacing ~32 cyc >= MFMA latency (fixes R12's dependency stall).
// H row = ct*32 + (b%6)*5 + ch; H in LDS [64][136] f16 (17408 B).
// bf (2x8 b128) register-held per layer; W streamed from L2, 4-deep
// rolling prefetch.
// ---------------------------------------------------------------------------
extern "C" __global__ __launch_bounds__(64, 2)
void pinn_mfma(const float* __restrict__ x, const float* __restrict__ t,
               const float* __restrict__ B, const uint32* __restrict__ Wp,
               const float* __restrict__ bh, const float* __restrict__ Wout,
               const float* __restrict__ bout, float* __restrict__ out, int npts)
{
    __shared__ __align__(16) unsigned short H[64][136];   // 17408 B

    const int lane = threadIdx.x;        // 0..63 (one wave)
    const int m31  = lane & 31;
    const int kg8  = (lane >> 5) * 8;    // k sub-offset (shorts)
    const int base_pt = blockIdx.x * NPTS_PER_WAVE;

    unsigned short* Hb = &H[0][0];

    // W frags: 4-deep rolling buffer; first 4 issued before the embed so
    // their L2 latency hides under the embedding math.
    uint4 wf[4];
    {
        const uint4* W0 = (const uint4*)Wp;
        #pragma unroll
        for (int p = 0; p < 4; ++p) wf[p] = W0[p * 64 + lane];
    }

    // ---------------- embedding (writes layer-0 H) ----------------
    {
        const float TWO_PI = 6.28318530717958647692f;
        const float Br0 = B[lane], Br1 = B[64 + lane], Br2 = B[128 + lane];
        const float b0 = TWO_PI * Br0, b1 = TWO_PI * Br1, b2 = TWO_PI * Br2;
        const float bsq = fmaf(b0, b0, b1 * b1);
        // zero the 4 pad rows (cols 30,31 of each tile never used downstream)
        Hb[30 * 136 + lane] = 0; Hb[30 * 136 + 64 + lane] = 0;
        Hb[31 * 136 + lane] = 0; Hb[31 * 136 + 64 + lane] = 0;
        Hb[62 * 136 + lane] = 0; Hb[62 * 136 + 64 + lane] = 0;
        Hb[63 * 136 + lane] = 0; Hb[63 * 136 + 64 + lane] = 0;
        #pragma unroll
        for (int pl = 0; pl < 6; ++pl) {
            int pt = base_pt + pl; if (pt > npts - 1) pt = npts - 1;
            const float2 xx = *(const float2*)&x[2 * pt];
            const float tt = t[pt];
            const float uc = fmaf(xx.y, Br1, tt * Br2);   // revolutions
            const float ux = xx.x * Br0;
            #pragma unroll
            for (int mir = 0; mir < 2; ++mir) {
                float u = mir ? (uc - ux) : (uc + ux);
                float r = u - floorf(u);
                float sf = __builtin_amdgcn_sinf(r);      // sin(2*pi*u)
                float cf = __builtin_amdgcn_cosf(r);      // cos(2*pi*u)
                const int b  = pl * 2 + mir;              // bp 0..11
                const int rs = (b / 6) * 32 + (b % 6) * 5;
                Hb[(rs + 0) * 136 + lane] = f2h(sf);
                Hb[(rs + 1) * 136 + lane] = f2h(cf * b2);
                Hb[(rs + 2) * 136 + lane] = f2h(cf * b0);
                Hb[(rs + 3) * 136 + lane] = f2h(cf * b1);
                Hb[(rs + 4) * 136 + lane] = f2h(-sf * bsq);
                Hb[(rs + 0) * 136 + 64 + lane] = f2h(cf);
                Hb[(rs + 1) * 136 + 64 + lane] = f2h(-sf * b2);
                Hb[(rs + 2) * 136 + 64 + lane] = f2h(-sf * b0);
                Hb[(rs + 3) * 136 + 64 + lane] = f2h(-sf * b1);
                Hb[(rs + 4) * 136 + 64 + lane] = f2h(-cf * bsq);
            }
        }
    }
    asm volatile("s_waitcnt lgkmcnt(0)" ::: "memory");

    // ---------------- hidden layers ----------------
    for (int L = 0; L < 4; ++L) {
        // B-fragments for both col-tiles, all 8 k-steps, held in registers
        // (must be read before any phase-A write overwrites H columns).
        h8 bf0[8], bf1[8];
        #pragma unroll
        for (int ks = 0; ks < 8; ++ks) {
            bf0[ks] = *(const h8*)&Hb[m31 * 136 + ks * 16 + kg8];
            bf1[ks] = *(const h8*)&Hb[(32 + m31) * 136 + ks * 16 + kg8];
        }

        const uint4* WL = (const uint4*)Wp + (size_t)L * 2048;   // layer base
        const uint4* WN = WL + 2048;                              // next layer

        #pragma unroll
        for (int jt = 0; jt < 4; ++jt) {
            f32x16 a0a = {0.f,0.f,0.f,0.f,0.f,0.f,0.f,0.f,0.f,0.f,0.f,0.f,0.f,0.f,0.f,0.f};
            f32x16 a0b = a0a, a1a = a0a, a1b = a0a;
            #pragma unroll
            for (int kp = 0; kp < 4; ++kp) {
                const int ks0 = 2 * kp, ks1 = 2 * kp + 1;
                const int fi0 = jt * 8 + ks0, fi1 = fi0 + 1;
                union { uint4 u; h8 v; } af0, af1;
                af0.u = wf[fi0 & 3];
                af1.u = wf[fi1 & 3];
                if (fi0 < 28)    wf[fi0 & 3] = WL[(fi0 + 4) * 64 + lane];
                else if (L < 3)  wf[fi0 & 3] = WN[(fi0 - 28) * 64 + lane];
                if (fi1 < 28)    wf[fi1 & 3] = WL[(fi1 + 4) * 64 + lane];
                else if (L < 3)  wf[fi1 & 3] = WN[(fi1 - 28) * 64 + lane];
                // 4 independent chains, round-robin issue
                a0a = __builtin_amdgcn_mfma_f32_32x32x16_f16(af0.v, bf0[ks0], a0a, 0, 0, 0);
                a1a = __builtin_amdgcn_mfma_f32_32x32x16_f16(af0.v, bf1[ks0], a1a, 0, 0, 0);
                a0b = __builtin_amdgcn_mfma_f32_32x32x16_f16(af1.v, bf0[ks1], a0b, 0, 0, 0);
                a1b = __builtin_amdgcn_mfma_f32_32x32x16_f16(af1.v, bf1[ks1], a1b, 0, 0, 0);
            }
            // phase A: merge partials + pack. C layout: col n = lane&31
            // (=H row within tile), row m = (reg&3)+8*(reg>>2)+4*(lane>>5).
            #pragma unroll
            for (int q = 0; q < 4; ++q) {
                union { h2 h[2]; uint2 u; } w0, w1;
                w0.h[0] = pkrtz(a0a[4*q+0] + a0b[4*q+0], a0a[4*q+1] + a0b[4*q+1]);
                w0.h[1] = pkrtz(a0a[4*q+2] + a0b[4*q+2], a0a[4*q+3] + a0b[4*q+3]);
                w1.h[0] = pkrtz(a1a[4*q+0] + a1b[4*q+0], a1a[4*q+1] + a1b[4*q+1]);
                w1.h[1] = pkrtz(a1a[4*q+2] + a1b[4*q+2], a1a[4*q+3] + a1b[4*q+3]);
                const int jof = jt * 32 + q * 8 + (lane >> 5) * 4;
                *(uint2*)&Hb[m31 * 136 + jof]        = w0.u;
                *(uint2*)&Hb[(32 + m31) * 136 + jof] = w1.u;
            }
        }
        asm volatile("s_waitcnt lgkmcnt(0)" ::: "memory");

        // phase B: lane-private j-columns (j = 2*lane, 2*lane+1), packed f16.
        // Bias (value channel only) applied here.
        {
            const int jb = 2 * lane;
            const float2 bj = *(const float2*)&bh[L * 128 + jb];
            const h2 bias2 = pkrtz(bj.x, bj.y);
            const h2 m2 = {(_Float16)(-2.0f), (_Float16)(-2.0f)};
            #pragma unroll
            for (int b = 0; b < 12; ++b) {
                const int rs = (b / 6) * 32 + (b % 6) * 5;
                h2 vp = *(const h2*)&Hb[(rs + 0) * 136 + jb];
                h2 tp = *(const h2*)&Hb[(rs + 1) * 136 + jb];
                h2 pp = *(const h2*)&Hb[(rs + 2) * 136 + jb];
                h2 qp = *(const h2*)&Hb[(rs + 3) * 136 + jb];
                h2 Lp = *(const h2*)&Hb[(rs + 4) * 136 + jb];
                vp = vp + bias2;
                float y0 = tanh_fast((float)vp[0]);
                float y1 = tanh_fast((float)vp[1]);
                h2 yp = pkrtz(y0, y1);
                h2 sp = pkrtz(fmaf(-y0, y0, 1.f), fmaf(-y1, y1, 1.f));
                h2 qq = __builtin_elementwise_fma(pp, pp, qp * qp);
                h2 Ln = sp * __builtin_elementwise_fma(yp * m2, qq, Lp);
                *(h2*)&Hb[(rs + 0) * 136 + jb] = yp;
                *(h2*)&Hb[(rs + 1) * 136 + jb] = sp * tp;
                *(h2*)&Hb[(rs + 2) * 136 + jb] = sp * pp;
                *(h2*)&Hb[(rs + 3) * 136 + jb] = sp * qp;
                *(h2*)&Hb[(rs + 4) * 136 + jb] = Ln;
            }
        }
        asm volatile("s_waitcnt lgkmcnt(0)" ::: "memory");
    }

    // ---------------- output layer via MFMA + residual ----------------
    {
        // A = Wout^T (2x128, rows 2..31 zeroed), built in-register
        h8 afo[8];
        const float sel = (m31 < 2) ? 1.0f : 0.0f;
        const int   mi  = m31 & 1;
        #pragma unroll
        for (int ks = 0; ks < 8; ++ks) {
            uint32 u[4];
            #pragma unroll
            for (int d = 0; d < 4; ++d) {
                const int k0 = ks * 16 + kg8 + 2 * d;
                u[d] = pk2h(Wout[k0 * 2 + mi] * sel, Wout[(k0 + 1) * 2 + mi] * sel);
            }
            afo[ks] = h8_from4(u[0], u[1], u[2], u[3]);
        }
        f32x16 a0a = {0.f,0.f,0.f,0.f,0.f,0.f,0.f,0.f,0.f,0.f,0.f,0.f,0.f,0.f,0.f,0.f};
        f32x16 a0b = a0a, a1a = a0a, a1b = a0a;
        #pragma unroll
        for (int kp = 0; kp < 4; ++kp) {
            const int ks0 = 2 * kp, ks1 = ks0 + 1;
            h8 b00 = *(const h8*)&Hb[m31 * 136 + ks0 * 16 + kg8];
            h8 b10 = *(const h8*)&Hb[(32 + m31) * 136 + ks0 * 16 + kg8];
            h8 b01 = *(const h8*)&Hb[m31 * 136 + ks1 * 16 + kg8];
            h8 b11 = *(const h8*)&Hb[(32 + m31) * 136 + ks1 * 16 + kg8];
            a0a = __builtin_amdgcn_mfma_f32_32x32x16_f16(afo[ks0], b00, a0a, 0, 0, 0);
            a1a = __builtin_amdgcn_mfma_f32_32x32x16_f16(afo[ks0], b10, a1a, 0, 0, 0);
            a0b = __builtin_amdgcn_mfma_f32_32x32x16_f16(afo[ks1], b01, a0b, 0, 0, 0);
            a1b = __builtin_amdgcn_mfma_f32_32x32x16_f16(afo[ks1], b11, a1b, 0, 0, 0);
        }
        // Lanes 0..31 hold C rows 0 (=o0, reg0) and 1 (=o1, reg1) for col n=lane.
        // S[n*4 + 2*ct + {0=o0,1=o1}]
        float* S = (float*)Hb;        // 512 B scratch, H no longer needed
        if (lane < 32) {
            f4 pack = {a0a[0] + a0b[0], a0a[1] + a0b[1],
                       a1a[0] + a1b[0], a1a[1] + a1b[1]};
            *(f4*)&S[lane * 4] = pack;
        }
        asm volatile("s_waitcnt lgkmcnt(0)" ::: "memory");

        if (lane < 6) {
            int pt = base_pt + lane;
            if (pt < npts) {
                float bo0 = bout[0], bo1 = bout[1];
                float ph = 0.f, cv = 0.f, ptd = 0.f, lp = 0.f;
                #pragma unroll
                for (int br = 0; br < 2; ++br) {
                    int b  = 2 * lane + br;
                    int ct = b / 6;
                    int n5 = (b % 6) * 5;
                    float o0v = S[(n5 + 0) * 4 + 2 * ct] + bo0;
                    float o0t = S[(n5 + 1) * 4 + 2 * ct];
                    float o0p = S[(n5 + 2) * 4 + 2 * ct];
                    float o0q = S[(n5 + 3) * 4 + 2 * ct];
                    float o0L = S[(n5 + 4) * 4 + 2 * ct];
                    float o1v = S[(n5 + 0) * 4 + 2 * ct + 1] + bo1;
                    float T = tanh_fast(o0v);
                    float p = fmaf(0.5f, T, 0.5f);
                    float s = 0.5f * fmaf(-T, T, 1.f);
                    float lap = s * o0L - 2.f * T * s * fmaf(o0p, o0p, o0q * o0q);
                    float cl = KCOEF * fmaf(0.5f, tanh_fast(o1v), 0.5f);
                    float cb = fmaf(DCOEF, (-2.f * p + 3.f) * p * p, cl);
                    ph  += 0.5f * p;
                    cv  += 0.5f * cb;
                    ptd += 0.5f * s * o0t;
                    lp  += 0.5f * lap;
                }
                float hph = (-2.f * ph + 3.f) * ph * ph;
                float dh  = 6.f * ph * (1.f - ph);
                float dg  = ((4.f * ph - 6.f) * ph + 2.f) * ph;
                float ac  = ptd
                          - 2.f * ((cv - hph * DCOEF - CLE_C) * DCOEF) * dh
                          + dg
                          - 0.01f * lp;
                out[pt] = ac;
            }
        }
    }
}

extern "C" void kernel_launch(void* const* d_in, const int* in_sizes, int n_in,
                              void* d_out, int out_size, void* d_ws, size_t ws_size,
                              hipStream_t stream) {
    const float* x    = (const float*)d_in[0];
    const float* t    = (const float*)d_in[1];
    const float* B    = (const float*)d_in[2];
    const float* Wh   = (const float*)d_in[3];
    const float* bh   = (const float*)d_in[4];
    const float* Wout = (const float*)d_in[5];
    const float* bout = (const float*)d_in[6];
    float* out = (float*)d_out;
    uint32* Wp = (uint32*)d_ws;                       // 128 KB scratch

    const int npts = in_sizes[0] / 2;
    hipLaunchKernelGGL(pinn_prep, dim3(128), dim3(256), 0, stream, Wh, Wp);
    const int nb = (npts + NPTS_PER_WAVE - 1) / NPTS_PER_WAVE;
    hipLaunchKernelGGL(pinn_mfma, dim3(nb), dim3(64), 0, stream,
                       x, t, B, Wp, bh, Wout, bout, out, npts);
}

// Round 15
// 133.276 us; speedup vs baseline: 1.0699x; 1.0475x over previous
//
#include <hip/hip_runtime.h>
#include <math.h>

#define NPTS_PER_WAVE 9

typedef _Float16 h8 __attribute__((ext_vector_type(8)));
typedef _Float16 h2 __attribute__((ext_vector_type(2)));
typedef __fp16   fp16x2 __attribute__((ext_vector_type(2)));
typedef float    f4 __attribute__((ext_vector_type(4)));
typedef unsigned int uint32;

// cfg constants
#define CSE_C 0.5f
#define CLE_C 0.00574f
#define DCOEF (CSE_C - CLE_C)          // 0.49426
#define KCOEF (1.0f - CSE_C + CLE_C)   // 0.50574

__device__ __forceinline__ float tanh_fast(float xx) {
    float e = __expf(2.0f * xx);
    float r = __builtin_amdgcn_rcpf(e + 1.0f);
    return fmaf(-2.0f, r, 1.0f);
}
__device__ __forceinline__ unsigned short f2h(float a) {
    union { _Float16 h; unsigned short u; } ua; ua.h = (_Float16)a; return ua.u;
}
__device__ __forceinline__ h2 pkrtz(float a, float b) {
    union { fp16x2 f; h2 h; } x; x.f = __builtin_amdgcn_cvt_pkrtz(a, b); return x.h;
}
__device__ __forceinline__ uint32 pk2h(float a, float b) {
    union { h2 h; uint32 u; } x; x.h = pkrtz(a, b); return x.u;
}
__device__ __forceinline__ h8 h8_from4(uint32 a, uint32 b, uint32 c, uint32 d) {
    union { uint32 u[4]; h8 v; } x; x.u[0] = a; x.u[1] = b; x.u[2] = c; x.u[3] = d;
    return x.v;
}

// ---------------------------------------------------------------------------
// Prep: Wh (4,128,128 f32) -> A-fragment-ordered f16 W^T tiles, [L][jo][kt]
// A-frag (16x16x32 f16): lane holds row m=lane&15, k=(lane>>4)*8+e.
//   Wp[ ((L*8+jo)*4+kt)*256 + lane*4 + d ] packs (k=kt*32+(lane>>4)*8+2d, k+1)
// value = W^T[m,k] = Wh[L][k][jout=jo*16+m]
// ---------------------------------------------------------------------------
extern "C" __global__ __launch_bounds__(256)
void pinn_prep(const float* __restrict__ Wh, uint32* __restrict__ Wp)
{
    int gid  = blockIdx.x * 256 + threadIdx.x;       // 0..32767
    int d    = gid & 3;
    int lane = (gid >> 2) & 63;
    int kt   = (gid >> 8) & 3;
    int jo   = (gid >> 10) & 7;
    int L    = gid >> 13;
    int j    = kt * 32 + (lane >> 4) * 8 + 2 * d;
    int jout = jo * 16 + (lane & 15);
    float w0 = Wh[(L * 128 + j) * 128 + jout];
    float w1 = Wh[(L * 128 + j + 1) * 128 + jout];
    Wp[gid] = pk2h(w0, w1);
}

// ---------------------------------------------------------------------------
// Main: barrier-free, 1 wave/block. One wave = 9 points = 18 branch-points
// (bp), 5 channels each: 0=value 1=d/dt 2=d/dx0 3=d/dx1 4=laplacian.
// 96 MFMA columns = 6 col-tiles of 16; bp b -> tile b/3, row off (b%3)*5.
// H in LDS [96][136] f16 (26112 B -> 6 blocks/CU). W streamed from L2 with
// 2-deep jo prefetch + cross-layer prefetch. 9 pts/wave cuts per-point W-L2
// traffic 33% vs 6 pts (the measured lever: R6/R11 wins, R12/R13 nulls).
// ---------------------------------------------------------------------------
extern "C" __global__ __launch_bounds__(64, 2)
void pinn_mfma(const float* __restrict__ x, const float* __restrict__ t,
               const float* __restrict__ B, const uint32* __restrict__ Wp,
               const float* __restrict__ bh, const float* __restrict__ Wout,
               const float* __restrict__ bout, float* __restrict__ out, int npts)
{
    __shared__ __align__(16) unsigned short H[96][136];   // 26112 B

    const int lane = threadIdx.x;        // 0..63 (one wave)
    const int c    = lane & 15;
    const int g    = lane >> 4;
    const int base_pt = blockIdx.x * NPTS_PER_WAVE;

    unsigned short* Hb = &H[0][0];

    // W tiles double-buffered; L0's first two tiles issued before the embed
    // so their L2 latency hides under the embedding math.
    uint4 wt[2][4];
    {
        const uint4* W0 = (const uint4*)Wp;
        #pragma unroll
        for (int kt = 0; kt < 4; ++kt) wt[0][kt] = W0[kt * 64 + lane];
        #pragma unroll
        for (int kt = 0; kt < 4; ++kt) wt[1][kt] = W0[(4 + kt) * 64 + lane];
    }

    // ---------------- embedding (writes layer-0 H) ----------------
    {
        const float TWO_PI = 6.28318530717958647692f;
        const float Br0 = B[lane], Br1 = B[64 + lane], Br2 = B[128 + lane];
        const float b0 = TWO_PI * Br0, b1 = TWO_PI * Br1, b2 = TWO_PI * Br2;
        const float bsq = fmaf(b0, b0, b1 * b1);
        #pragma unroll
        for (int pl = 0; pl < 9; ++pl) {
            int pt = base_pt + pl; if (pt > npts - 1) pt = npts - 1;
            const float2 xx = *(const float2*)&x[2 * pt];
            const float tt = t[pt];
            const float uc = fmaf(xx.y, Br1, tt * Br2);   // revolutions
            const float ux = xx.x * Br0;
            #pragma unroll
            for (int mir = 0; mir < 2; ++mir) {
                float u = mir ? (uc - ux) : (uc + ux);
                float r = u - floorf(u);
                float sf = __builtin_amdgcn_sinf(r);      // sin(2*pi*u)
                float cf = __builtin_amdgcn_cosf(r);      // cos(2*pi*u)
                const int b  = pl * 2 + mir;              // bp 0..17
                const int rs = (b / 3) * 16 + (b % 3) * 5;
                Hb[(rs + 0) * 136 + lane] = f2h(sf);
                Hb[(rs + 1) * 136 + lane] = f2h(cf * b2);
                Hb[(rs + 2) * 136 + lane] = f2h(cf * b0);
                Hb[(rs + 3) * 136 + lane] = f2h(cf * b1);
                Hb[(rs + 4) * 136 + lane] = f2h(-sf * bsq);
                Hb[(rs + 0) * 136 + 64 + lane] = f2h(cf);
                Hb[(rs + 1) * 136 + 64 + lane] = f2h(-sf * b2);
                Hb[(rs + 2) * 136 + 64 + lane] = f2h(-sf * b0);
                Hb[(rs + 3) * 136 + 64 + lane] = f2h(-sf * b1);
                Hb[(rs + 4) * 136 + 64 + lane] = f2h(-cf * bsq);
            }
        }
    }
    asm volatile("s_waitcnt lgkmcnt(0)" ::: "memory");

    // ---------------- hidden layers ----------------
    for (int L = 0; L < 4; ++L) {
        // B-fragments: row = ct*16+c, k cols kt*32+g*8..+7
        h8 bf[6][4];
        #pragma unroll
        for (int ct = 0; ct < 6; ++ct)
            #pragma unroll
            for (int kt = 0; kt < 4; ++kt)
                bf[ct][kt] = *(const h8*)&Hb[(ct * 16 + c) * 136 + kt * 32 + g * 8];

        const uint4* WL = (const uint4*)Wp + (size_t)L * 2048;   // layer base
        const uint4* WN = WL + 2048;                              // next layer

        #pragma unroll
        for (int jo = 0; jo < 8; ++jo) {
            const int cur = jo & 1;
            f4 a0 = {0.f,0.f,0.f,0.f}, a1 = a0, a2 = a0, a3 = a0, a4 = a0, a5 = a0;
            #pragma unroll
            for (int kt = 0; kt < 4; ++kt) {
                union { uint4 u; h8 v; } af;
                af.u = wt[cur][kt];
                a0 = __builtin_amdgcn_mfma_f32_16x16x32_f16(af.v, bf[0][kt], a0, 0, 0, 0);
                a1 = __builtin_amdgcn_mfma_f32_16x16x32_f16(af.v, bf[1][kt], a1, 0, 0, 0);
                a2 = __builtin_amdgcn_mfma_f32_16x16x32_f16(af.v, bf[2][kt], a2, 0, 0, 0);
                a3 = __builtin_amdgcn_mfma_f32_16x16x32_f16(af.v, bf[3][kt], a3, 0, 0, 0);
                a4 = __builtin_amdgcn_mfma_f32_16x16x32_f16(af.v, bf[4][kt], a4, 0, 0, 0);
                a5 = __builtin_amdgcn_mfma_f32_16x16x32_f16(af.v, bf[5][kt], a5, 0, 0, 0);
            }
            // refill consumed buffer: jo+2 of this layer, or next layer's 0/1
            if (jo < 6) {
                #pragma unroll
                for (int kt = 0; kt < 4; ++kt)
                    wt[cur][kt] = WL[((jo + 2) * 4 + kt) * 64 + lane];
            } else if (L < 3) {
                #pragma unroll
                for (int kt = 0; kt < 4; ++kt)
                    wt[cur][kt] = WN[((jo - 6) * 4 + kt) * 64 + lane];
            }
            // phase A: raw pre-activations (row=ct*16+c, col j=jo*16+g*4+r)
            {
                union { h2 h[2]; uint2 u; } w;
                const int jof = jo * 16 + g * 4;
                w.h[0] = pkrtz(a0[0], a0[1]); w.h[1] = pkrtz(a0[2], a0[3]);
                *(uint2*)&Hb[(0  + c) * 136 + jof] = w.u;
                w.h[0] = pkrtz(a1[0], a1[1]); w.h[1] = pkrtz(a1[2], a1[3]);
                *(uint2*)&Hb[(16 + c) * 136 + jof] = w.u;
                w.h[0] = pkrtz(a2[0], a2[1]); w.h[1] = pkrtz(a2[2], a2[3]);
                *(uint2*)&Hb[(32 + c) * 136 + jof] = w.u;
                w.h[0] = pkrtz(a3[0], a3[1]); w.h[1] = pkrtz(a3[2], a3[3]);
                *(uint2*)&Hb[(48 + c) * 136 + jof] = w.u;
                w.h[0] = pkrtz(a4[0], a4[1]); w.h[1] = pkrtz(a4[2], a4[3]);
                *(uint2*)&Hb[(64 + c) * 136 + jof] = w.u;
                w.h[0] = pkrtz(a5[0], a5[1]); w.h[1] = pkrtz(a5[2], a5[3]);
                *(uint2*)&Hb[(80 + c) * 136 + jof] = w.u;
            }
        }
        asm volatile("s_waitcnt lgkmcnt(0)" ::: "memory");

        // phase B: lane-private j-columns (j = 2*lane, 2*lane+1), packed f16.
        // Bias (value channel only) applied here.
        {
            const int jb = 2 * lane;
            const float2 bj = *(const float2*)&bh[L * 128 + jb];
            const h2 bias2 = pkrtz(bj.x, bj.y);
            const h2 m2 = {(_Float16)(-2.0f), (_Float16)(-2.0f)};
            #pragma unroll
            for (int b = 0; b < 18; ++b) {
                const int rs = (b / 3) * 16 + (b % 3) * 5;
                h2 vp = *(const h2*)&Hb[(rs + 0) * 136 + jb];
                h2 tp = *(const h2*)&Hb[(rs + 1) * 136 + jb];
                h2 pp = *(const h2*)&Hb[(rs + 2) * 136 + jb];
                h2 qp = *(const h2*)&Hb[(rs + 3) * 136 + jb];
                h2 Lp = *(const h2*)&Hb[(rs + 4) * 136 + jb];
                vp = vp + bias2;
                float y0 = tanh_fast((float)vp[0]);
                float y1 = tanh_fast((float)vp[1]);
                h2 yp = pkrtz(y0, y1);
                h2 sp = pkrtz(fmaf(-y0, y0, 1.f), fmaf(-y1, y1, 1.f));
                h2 qq = __builtin_elementwise_fma(pp, pp, qp * qp);
                h2 Ln = sp * __builtin_elementwise_fma(yp * m2, qq, Lp);
                *(h2*)&Hb[(rs + 0) * 136 + jb] = yp;
                *(h2*)&Hb[(rs + 1) * 136 + jb] = sp * tp;
                *(h2*)&Hb[(rs + 2) * 136 + jb] = sp * pp;
                *(h2*)&Hb[(rs + 3) * 136 + jb] = sp * qp;
                *(h2*)&Hb[(rs + 4) * 136 + jb] = Ln;
            }
        }
        asm volatile("s_waitcnt lgkmcnt(0)" ::: "memory");
    }

    // ---------------- output layer via MFMA + residual ----------------
    {
        // A = Wout^T (2x128, rows 2..15 zeroed), built in-register
        h8 afo[4];
        const int   mc  = c & 1;
        const float sel = (c < 2) ? 1.0f : 0.0f;
        #pragma unroll
        for (int kt = 0; kt < 4; ++kt) {
            uint32 u[4];
            #pragma unroll
            for (int d = 0; d < 4; ++d) {
                int k = kt * 32 + g * 8 + 2 * d;
                float w0 = Wout[k * 2 + mc] * sel;
                float w1 = Wout[(k + 1) * 2 + mc] * sel;
                u[d] = pk2h(w0, w1);
            }
            afo[kt] = h8_from4(u[0], u[1], u[2], u[3]);
        }
        // B = final H (same fragment pattern as hidden layers)
        f4 ac[6];
        #pragma unroll
        for (int ct = 0; ct < 6; ++ct) { ac[ct] = f4{0.f, 0.f, 0.f, 0.f}; }
        #pragma unroll
        for (int kt = 0; kt < 4; ++kt) {
            #pragma unroll
            for (int ct = 0; ct < 6; ++ct) {
                h8 bfo = *(const h8*)&Hb[(ct * 16 + c) * 136 + kt * 32 + g * 8];
                ac[ct] = __builtin_amdgcn_mfma_f32_16x16x32_f16(afo[kt], bfo, ac[ct], 0, 0, 0);
            }
        }
        // g==0 lanes hold rows 0 (=o0) and 1 (=o1) for col c of each tile.
        // S[(ct*16 + c)*2 + {0=o0,1=o1}]
        float* S = (float*)Hb;        // 768 B scratch, H no longer needed
        if (g == 0) {
            #pragma unroll
            for (int ct = 0; ct < 6; ++ct) {
                float2 pk = {ac[ct][0], ac[ct][1]};
                *(float2*)&S[(ct * 16 + c) * 2] = pk;
            }
        }
        asm volatile("s_waitcnt lgkmcnt(0)" ::: "memory");

        if (lane < 9) {
            int pt = base_pt + lane;
            if (pt < npts) {
                float bo0 = bout[0], bo1 = bout[1];
                float ph = 0.f, cv = 0.f, ptd = 0.f, lp = 0.f;
                #pragma unroll
                for (int br = 0; br < 2; ++br) {
                    int b  = 2 * lane + br;
                    int ct = b / 3;
                    int cc = (b % 3) * 5;
                    const float* Sc = &S[(ct * 16 + cc) * 2];
                    float o0v = Sc[0] + bo0;
                    float o1v = Sc[1] + bo1;
                    float o0t = Sc[2];
                    float o0p = Sc[4];
                    float o0q = Sc[6];
                    float o0L = Sc[8];
                    float T = tanh_fast(o0v);
                    float p = fmaf(0.5f, T, 0.5f);
                    float s = 0.5f * fmaf(-T, T, 1.f);
                    float lap = s * o0L - 2.f * T * s * fmaf(o0p, o0p, o0q * o0q);
                    float cl = KCOEF * fmaf(0.5f, tanh_fast(o1v), 0.5f);
                    float cb = fmaf(DCOEF, (-2.f * p + 3.f) * p * p, cl);
                    ph  += 0.5f * p;
                    cv  += 0.5f * cb;
                    ptd += 0.5f * s * o0t;
                    lp  += 0.5f * lap;
                }
                float hph = (-2.f * ph + 3.f) * ph * ph;
                float dh  = 6.f * ph * (1.f - ph);
                float dg  = ((4.f * ph - 6.f) * ph + 2.f) * ph;
                float ac2 = ptd
                          - 2.f * ((cv - hph * DCOEF - CLE_C) * DCOEF) * dh
                          + dg
                          - 0.01f * lp;
                out[pt] = ac2;
            }
        }
    }
}

extern "C" void kernel_launch(void* const* d_in, const int* in_sizes, int n_in,
                              void* d_out, int out_size, void* d_ws, size_t ws_size,
                              hipStream_t stream) {
    const float* x    = (const float*)d_in[0];
    const float* t    = (const float*)d_in[1];
    const float* B    = (const float*)d_in[2];
    const float* Wh   = (const float*)d_in[3];
    const float* bh   = (const float*)d_in[4];
    const float* Wout = (const float*)d_in[5];
    const float* bout = (const float*)d_in[6];
    float* out = (float*)d_out;
    uint32* Wp = (uint32*)d_ws;                       // 128 KB scratch

    const int npts = in_sizes[0] / 2;
    hipLaunchKernelGGL(pinn_prep, dim3(128), dim3(256), 0, stream, Wh, Wp);
    const int nb = (npts + NPTS_PER_WAVE - 1) / NPTS_PER_WAVE;
    hipLaunchKernelGGL(pinn_mfma, dim3(nb), dim3(64), 0, stream,
                       x, t, B, Wp, bh, Wout, bout, out, npts);
}

// Round 16
// 122.325 us; speedup vs baseline: 1.1657x; 1.0895x over previous
//
#include <hip/hip_runtime.h>
#include <math.h>

#define NPTS_PER_WAVE 6

typedef _Float16 h8 __attribute__((ext_vector_type(8)));
typedef _Float16 h2 __attribute__((ext_vector_type(2)));
typedef __fp16   fp16x2 __attribute__((ext_vector_type(2)));
typedef float    f4 __attribute__((ext_vector_type(4)));
typedef unsigned int uint32;

// cfg constants
#define CSE_C 0.5f
#define CLE_C 0.00574f
#define DCOEF (CSE_C - CLE_C)          // 0.49426
#define KCOEF (1.0f - CSE_C + CLE_C)   // 0.50574

__device__ __forceinline__ float tanh_fast(float xx) {
    float e = __expf(2.0f * xx);
    float r = __builtin_amdgcn_rcpf(e + 1.0f);
    return fmaf(-2.0f, r, 1.0f);
}
__device__ __forceinline__ unsigned short f2h(float a) {
    union { _Float16 h; unsigned short u; } ua; ua.h = (_Float16)a; return ua.u;
}
__device__ __forceinline__ h2 pkrtz(float a, float b) {
    union { fp16x2 f; h2 h; } x; x.f = __builtin_amdgcn_cvt_pkrtz(a, b); return x.h;
}
__device__ __forceinline__ uint32 pk2h(float a, float b) {
    union { h2 h; uint32 u; } x; x.h = pkrtz(a, b); return x.u;
}
__device__ __forceinline__ h8 h8_from4(uint32 a, uint32 b, uint32 c, uint32 d) {
    union { uint32 u[4]; h8 v; } x; x.u[0] = a; x.u[1] = b; x.u[2] = c; x.u[3] = d;
    return x.v;
}

// ---------------------------------------------------------------------------
// Prep: Wh (4,128,128 f32) -> A-fragment-ordered f16 W^T tiles, [L][jo][kt]
// A-frag (16x16x32 f16): lane holds row m=lane&15, k=(lane>>4)*8+e.
//   Wp[ ((L*8+jo)*4+kt)*256 + lane*4 + d ] packs (k=kt*32+(lane>>4)*8+2d, k+1)
// value = W^T[m,k] = Wh[L][k][jout=jo*16+m]
// ---------------------------------------------------------------------------
extern "C" __global__ __launch_bounds__(256)
void pinn_prep(const float* __restrict__ Wh, uint32* __restrict__ Wp)
{
    int gid  = blockIdx.x * 256 + threadIdx.x;       // 0..32767
    int d    = gid & 3;
    int lane = (gid >> 2) & 63;
    int kt   = (gid >> 8) & 3;
    int jo   = (gid >> 10) & 7;
    int L    = gid >> 13;
    int j    = kt * 32 + (lane >> 4) * 8 + 2 * d;
    int jout = jo * 16 + (lane & 15);
    float w0 = Wh[(L * 128 + j) * 128 + jout];
    float w1 = Wh[(L * 128 + j + 1) * 128 + jout];
    Wp[gid] = pk2h(w0, w1);
}

// ---------------------------------------------------------------------------
// Main: barrier-free, 1 wave/block. One wave = 6 points = 12 branch-points
// (bp), 5 channels each: 0=value 1=d/dt 2=d/dx0 3=d/dx1 4=laplacian.
// 64 MFMA columns = 4 col-tiles x (3bp x 5ch + pad); bp b -> tile b/3,
// row offset (b%3)*5. H in LDS [64][136] f16 (17408 B, 9 blocks/CU).
// W streamed from L2 with a 4-DEEP rolling prefetch (issue-to-use ~3 jo
// ~700-1000 cyc >> contended L2 latency; 16 loads in flight per wave).
// L2 BW is only ~32% used at this rate -- the stall was MLP, not BW.
// ---------------------------------------------------------------------------
extern "C" __global__ __launch_bounds__(64, 2)
void pinn_mfma(const float* __restrict__ x, const float* __restrict__ t,
               const float* __restrict__ B, const uint32* __restrict__ Wp,
               const float* __restrict__ bh, const float* __restrict__ Wout,
               const float* __restrict__ bout, float* __restrict__ out, int npts)
{
    __shared__ __align__(16) unsigned short H[64][136];   // 17408 B

    const int lane = threadIdx.x;        // 0..63 (one wave)
    const int c    = lane & 15;
    const int g    = lane >> 4;
    const int base_pt = blockIdx.x * NPTS_PER_WAVE;

    unsigned short* Hb = &H[0][0];

    // W tiles: 4-deep rolling buffer; L0's tiles 0..3 issued before the
    // embed so their L2 latency hides under the embedding math.
    uint4 wt[4][4];
    {
        const uint4* W0 = (const uint4*)Wp;
        #pragma unroll
        for (int p = 0; p < 4; ++p)
            #pragma unroll
            for (int kt = 0; kt < 4; ++kt)
                wt[p][kt] = W0[(p * 4 + kt) * 64 + lane];
    }

    // ---------------- embedding (writes layer-0 H) ----------------
    {
        const float TWO_PI = 6.28318530717958647692f;
        const float Br0 = B[lane], Br1 = B[64 + lane], Br2 = B[128 + lane];
        const float b0 = TWO_PI * Br0, b1 = TWO_PI * Br1, b2 = TWO_PI * Br2;
        const float bsq = fmaf(b0, b0, b1 * b1);
        #pragma unroll
        for (int pl = 0; pl < 6; ++pl) {
            int pt = base_pt + pl; if (pt > npts - 1) pt = npts - 1;
            const float2 xx = *(const float2*)&x[2 * pt];
            const float tt = t[pt];
            const float uc = fmaf(xx.y, Br1, tt * Br2);   // revolutions
            const float ux = xx.x * Br0;
            #pragma unroll
            for (int mir = 0; mir < 2; ++mir) {
                float u = mir ? (uc - ux) : (uc + ux);
                float r = u - floorf(u);
                float sf = __builtin_amdgcn_sinf(r);      // sin(2*pi*u)
                float cf = __builtin_amdgcn_cosf(r);      // cos(2*pi*u)
                const int b  = pl * 2 + mir;              // bp 0..11
                const int rs = (b / 3) * 16 + (b % 3) * 5;
                Hb[(rs + 0) * 136 + lane] = f2h(sf);
                Hb[(rs + 1) * 136 + lane] = f2h(cf * b2);
                Hb[(rs + 2) * 136 + lane] = f2h(cf * b0);
                Hb[(rs + 3) * 136 + lane] = f2h(cf * b1);
                Hb[(rs + 4) * 136 + lane] = f2h(-sf * bsq);
                Hb[(rs + 0) * 136 + 64 + lane] = f2h(cf);
                Hb[(rs + 1) * 136 + 64 + lane] = f2h(-sf * b2);
                Hb[(rs + 2) * 136 + 64 + lane] = f2h(-sf * b0);
                Hb[(rs + 3) * 136 + 64 + lane] = f2h(-sf * b1);
                Hb[(rs + 4) * 136 + 64 + lane] = f2h(-cf * bsq);
            }
        }
    }
    asm volatile("s_waitcnt lgkmcnt(0)" ::: "memory");

    // ---------------- hidden layers ----------------
    for (int L = 0; L < 4; ++L) {
        // B-fragments: row = ct*16+c, k cols kt*32+g*8..+7
        h8 bf[4][4];
        #pragma unroll
        for (int ct = 0; ct < 4; ++ct)
            #pragma unroll
            for (int kt = 0; kt < 4; ++kt)
                bf[ct][kt] = *(const h8*)&Hb[(ct * 16 + c) * 136 + kt * 32 + g * 8];

        const uint4* WL = (const uint4*)Wp + (size_t)L * 2048;   // layer base
        const uint4* WN = WL + 2048;                              // next layer

        #pragma unroll
        for (int jo = 0; jo < 8; ++jo) {
            const int cur = jo & 3;
            f4 a0 = {0.f, 0.f, 0.f, 0.f}, a1 = a0, a2 = a0, a3 = a0;
            #pragma unroll
            for (int kt = 0; kt < 4; ++kt) {
                union { uint4 u; h8 v; } af;
                af.u = wt[cur][kt];
                a0 = __builtin_amdgcn_mfma_f32_16x16x32_f16(af.v, bf[0][kt], a0, 0, 0, 0);
                a1 = __builtin_amdgcn_mfma_f32_16x16x32_f16(af.v, bf[1][kt], a1, 0, 0, 0);
                a2 = __builtin_amdgcn_mfma_f32_16x16x32_f16(af.v, bf[2][kt], a2, 0, 0, 0);
                a3 = __builtin_amdgcn_mfma_f32_16x16x32_f16(af.v, bf[3][kt], a3, 0, 0, 0);
            }
            // refill consumed slot: jo+4 of this layer, or next layer's jo-4
            if (jo < 4) {
                #pragma unroll
                for (int kt = 0; kt < 4; ++kt)
                    wt[cur][kt] = WL[((jo + 4) * 4 + kt) * 64 + lane];
            } else if (L < 3) {
                #pragma unroll
                for (int kt = 0; kt < 4; ++kt)
                    wt[cur][kt] = WN[((jo - 4) * 4 + kt) * 64 + lane];
            }
            // phase A: raw pre-activations (row=ct*16+c, col j=jo*16+g*4+r)
            {
                union { h2 h[2]; uint2 u; } w;
                const int jof = jo * 16 + g * 4;
                w.h[0] = pkrtz(a0[0], a0[1]); w.h[1] = pkrtz(a0[2], a0[3]);
                *(uint2*)&Hb[(0  + c) * 136 + jof] = w.u;
                w.h[0] = pkrtz(a1[0], a1[1]); w.h[1] = pkrtz(a1[2], a1[3]);
                *(uint2*)&Hb[(16 + c) * 136 + jof] = w.u;
                w.h[0] = pkrtz(a2[0], a2[1]); w.h[1] = pkrtz(a2[2], a2[3]);
                *(uint2*)&Hb[(32 + c) * 136 + jof] = w.u;
                w.h[0] = pkrtz(a3[0], a3[1]); w.h[1] = pkrtz(a3[2], a3[3]);
                *(uint2*)&Hb[(48 + c) * 136 + jof] = w.u;
            }
        }
        asm volatile("s_waitcnt lgkmcnt(0)" ::: "memory");

        // phase B: lane-private j-columns (j = 2*lane, 2*lane+1), packed f16.
        // Bias (value channel only) applied here.
        {
            const int jb = 2 * lane;
            const float2 bj = *(const float2*)&bh[L * 128 + jb];
            const h2 bias2 = pkrtz(bj.x, bj.y);
            const h2 m2 = {(_Float16)(-2.0f), (_Float16)(-2.0f)};
            #pragma unroll
            for (int b = 0; b < 12; ++b) {
                const int rs = (b / 3) * 16 + (b % 3) * 5;
                h2 vp = *(const h2*)&Hb[(rs + 0) * 136 + jb];
                h2 tp = *(const h2*)&Hb[(rs + 1) * 136 + jb];
                h2 pp = *(const h2*)&Hb[(rs + 2) * 136 + jb];
                h2 qp = *(const h2*)&Hb[(rs + 3) * 136 + jb];
                h2 Lp = *(const h2*)&Hb[(rs + 4) * 136 + jb];
                vp = vp + bias2;
                float y0 = tanh_fast((float)vp[0]);
                float y1 = tanh_fast((float)vp[1]);
                h2 yp = pkrtz(y0, y1);
                h2 sp = pkrtz(fmaf(-y0, y0, 1.f), fmaf(-y1, y1, 1.f));
                h2 qq = __builtin_elementwise_fma(pp, pp, qp * qp);
                h2 Ln = sp * __builtin_elementwise_fma(yp * m2, qq, Lp);
                *(h2*)&Hb[(rs + 0) * 136 + jb] = yp;
                *(h2*)&Hb[(rs + 1) * 136 + jb] = sp * tp;
                *(h2*)&Hb[(rs + 2) * 136 + jb] = sp * pp;
                *(h2*)&Hb[(rs + 3) * 136 + jb] = sp * qp;
                *(h2*)&Hb[(rs + 4) * 136 + jb] = Ln;
            }
        }
        asm volatile("s_waitcnt lgkmcnt(0)" ::: "memory");
    }

    // ---------------- output layer via MFMA + residual ----------------
    {
        // A = Wout^T (2x128, rows 2..15 zeroed), built in-register
        h8 afo[4];
        const int   mc  = c & 1;
        const float sel = (c < 2) ? 1.0f : 0.0f;
        #pragma unroll
        for (int kt = 0; kt < 4; ++kt) {
            uint32 u[4];
            #pragma unroll
            for (int d = 0; d < 4; ++d) {
                int k = kt * 32 + g * 8 + 2 * d;
                float w0 = Wout[k * 2 + mc] * sel;
                float w1 = Wout[(k + 1) * 2 + mc] * sel;
                u[d] = pk2h(w0, w1);
            }
            afo[kt] = h8_from4(u[0], u[1], u[2], u[3]);
        }
        // B = final H (same fragment pattern as hidden layers)
        f4 ac[4];
        #pragma unroll
        for (int ct = 0; ct < 4; ++ct) ac[ct] = f4{0.f, 0.f, 0.f, 0.f};
        #pragma unroll
        for (int kt = 0; kt < 4; ++kt) {
            #pragma unroll
            for (int ct = 0; ct < 4; ++ct) {
                h8 bfo = *(const h8*)&Hb[(ct * 16 + c) * 136 + kt * 32 + g * 8];
                ac[ct] = __builtin_amdgcn_mfma_f32_16x16x32_f16(afo[kt], bfo, ac[ct], 0, 0, 0);
            }
        }
        // g==0 lanes hold rows 0 (=o0) and 1 (=o1) for col c of each tile.
        // S[(ct*16 + c)*2 + {0=o0,1=o1}]
        float* S = (float*)Hb;        // 512 B scratch, H no longer needed
        if (g == 0) {
            #pragma unroll
            for (int ct = 0; ct < 4; ++ct) {
                float2 pk = {ac[ct][0], ac[ct][1]};
                *(float2*)&S[(ct * 16 + c) * 2] = pk;
            }
        }
        asm volatile("s_waitcnt lgkmcnt(0)" ::: "memory");

        if (lane < 6) {
            int pt = base_pt + lane;
            if (pt < npts) {
                float bo0 = bout[0], bo1 = bout[1];
                float ph = 0.f, cv = 0.f, ptd = 0.f, lp = 0.f;
                #pragma unroll
                for (int br = 0; br < 2; ++br) {
                    int b  = 2 * lane + br;
                    int ct = b / 3;
                    int cc = (b % 3) * 5;
                    const float* Sc = &S[(ct * 16 + cc) * 2];
                    float o0v = Sc[0] + bo0;
                    float o1v = Sc[1] + bo1;
                    float o0t = Sc[2];
                    float o0p = Sc[4];
                    float o0q = Sc[6];
                    float o0L = Sc[8];
                    float T = tanh_fast(o0v);
                    float p = fmaf(0.5f, T, 0.5f);
                    float s = 0.5f * fmaf(-T, T, 1.f);
                    float lap = s * o0L - 2.f * T * s * fmaf(o0p, o0p, o0q * o0q);
                    float cl = KCOEF * fmaf(0.5f, tanh_fast(o1v), 0.5f);
                    float cb = fmaf(DCOEF, (-2.f * p + 3.f) * p * p, cl);
                    ph  += 0.5f * p;
                    cv  += 0.5f * cb;
                    ptd += 0.5f * s * o0t;
                    lp  += 0.5f * lap;
                }
                float hph = (-2.f * ph + 3.f) * ph * ph;
                float dh  = 6.f * ph * (1.f - ph);
                float dg  = ((4.f * ph - 6.f) * ph + 2.f) * ph;
                float ac2 = ptd
                          - 2.f * ((cv - hph * DCOEF - CLE_C) * DCOEF) * dh
                          + dg
                          - 0.01f * lp;
                out[pt] = ac2;
            }
        }
    }
}

extern "C" void kernel_launch(void* const* d_in, const int* in_sizes, int n_in,
                              void* d_out, int out_size, void* d_ws, size_t ws_size,
                              hipStream_t stream) {
    const float* x    = (const float*)d_in[0];
    const float* t    = (const float*)d_in[1];
    const float* B    = (const float*)d_in[2];
    const float* Wh   = (const float*)d_in[3];
    const float* bh   = (const float*)d_in[4];
    const float* Wout = (const float*)d_in[5];
    const float* bout = (const float*)d_in[6];
    float* out = (float*)d_out;
    uint32* Wp = (uint32*)d_ws;                       // 128 KB scratch

    const int npts = in_sizes[0] / 2;
    hipLaunchKernelGGL(pinn_prep, dim3(128), dim3(256), 0, stream, Wh, Wp);
    const int nb = (npts + NPTS_PER_WAVE - 1) / NPTS_PER_WAVE;
    hipLaunchKernelGGL(pinn_mfma, dim3(nb), dim3(64), 0, stream,
                       x, t, B, Wp, bh, Wout, bout, out, npts);
}